// Round 1
// baseline (412.929 us; speedup 1.0000x reference)
//
#include <hip/hip_runtime.h>

// SPA (second-price auction) payment kernel.
// x: (BATCH, 16) fp32. Per row: top-2 (m1, m2). out[j] = (x[j]==m1 ? m2 : m1), clamped >= 0.
// Tie semantics: if >=2 elements equal m1, then m2==m1, so the elementwise form matches
// the reference's first-argmax form exactly.
//
// Layout: 4 lanes per row, float4 per lane (fully coalesced, 16B/lane).
// Top-2 merged across the 4 lanes with two shfl_xor rounds.

__global__ __launch_bounds__(256) void _SpaPayment_88399016886488_kernel(
    const float4* __restrict__ x, float4* __restrict__ out, int nquads) {
    int tid = blockIdx.x * blockDim.x + threadIdx.x;
    if (tid >= nquads) return;

    float4 v = x[tid];

    // local top-2 of 4 elements (counting duplicates)
    float a = fmaxf(v.x, v.y), b = fminf(v.x, v.y);
    float c = fmaxf(v.z, v.w), d = fminf(v.z, v.w);
    float m1 = fmaxf(a, c);
    float m2 = fmaxf(fminf(a, c), fmaxf(b, d));

    // merge (m1,m2) across the 4 lanes of this row (lanes tid^1, tid^2)
    #pragma unroll
    for (int off = 1; off <= 2; off <<= 1) {
        float o1 = __shfl_xor(m1, off);
        float o2 = __shfl_xor(m2, off);
        float hi = fmaxf(m1, o1);
        float lo = fminf(m1, o1);
        m1 = hi;
        m2 = fmaxf(lo, fmaxf(m2, o2));
    }

    float4 o;
    o.x = fmaxf((v.x == m1) ? m2 : m1, 0.0f);
    o.y = fmaxf((v.y == m1) ? m2 : m1, 0.0f);
    o.z = fmaxf((v.z == m1) ? m2 : m1, 0.0f);
    o.w = fmaxf((v.w == m1) ? m2 : m1, 0.0f);
    out[tid] = o;
}

extern "C" void kernel_launch(void* const* d_in, const int* in_sizes, int n_in,
                              void* d_out, int out_size, void* d_ws, size_t ws_size,
                              hipStream_t stream) {
    const float4* x = (const float4*)d_in[0];
    float4* out = (float4*)d_out;
    int n = in_sizes[0];          // 4194304 * 16 elements
    int nquads = n / 4;           // 16777216 float4s
    int block = 256;
    int grid = (nquads + block - 1) / block;
    _SpaPayment_88399016886488_kernel<<<grid, block, 0, stream>>>(x, out, nquads);
}